// Round 5
// baseline (4154.336 us; speedup 1.0000x reference)
//
#include <hip/hip_runtime.h>
#include <math.h>

// Problem constants: T=512, B=64, I=256, H=1024, O=256
// d_out layout: outputs [512*64][256] fp32, then hidden_states [512*64][1024] fp32.

typedef __attribute__((ext_vector_type(8))) short s16x8;
typedef __attribute__((ext_vector_type(4))) short s16x4;
typedef __attribute__((ext_vector_type(4))) float f32x4;
typedef unsigned long long u64;

__device__ __forceinline__ short f2bf(float f) {
  union { float f; unsigned u; } v; v.f = f;
  unsigned r = v.u + 0x7FFFu + ((v.u >> 16) & 1u);  // RNE
  return (short)(r >> 16);
}

__device__ __forceinline__ f32x4 mfma16(s16x8 a, s16x8 b, f32x4 c) {
  return __builtin_amdgcn_mfma_f32_16x16x32_bf16(a, b, c, 0, 0, 0);
}

// tanh via v_exp_f32: t = 1 - 2/(e^{2x}+1). Monotone-safe at +-inf, no NaN.
__device__ __forceinline__ float fast_tanh(float x) {
  float e = __expf(2.0f * x);
  return 1.0f - 2.0f * __builtin_amdgcn_rcpf(e + 1.0f);
}

// ---------------- converters / init ----------------

__global__ void cvt_bf16x4(const float* __restrict__ in, short* __restrict__ out, int n4) {
  int i = blockIdx.x * 256 + threadIdx.x;
  if (i < n4) {
    const float4 v = ((const float4*)in)[i];
    s16x4 o = { f2bf(v.x), f2bf(v.y), f2bf(v.z), f2bf(v.w) };
    ((s16x4*)out)[i] = o;
  }
}

// staging32: [2 slots][64 rows][1024] tagged dwords: (bf16 << 16) | step_tag.
// slot1 = h_{-1} = broadcast h0, tag 0 (consumer at t=0 expects tag 0).
// slot0 zeroed: tag 0 never matches its first expected tag (1).
__global__ void init_staging32(const float* __restrict__ h0, unsigned* __restrict__ staging) {
  int i = blockIdx.x * 256 + threadIdx.x;  // 2*64*1024 = 131072
  if (i < 131072) {
    int slot = i >> 16;
    int k = i & 1023;
    staging[i] = slot ? (((unsigned)(unsigned short)f2bf(h0[k])) << 16) : 0u;
  }
}

// ---------------- generic NT GEMM: out[M][N] = A[M][K](bf16) * B[N][K](bf16)^T + bias ----------------

template <int K>
__global__ __launch_bounds__(256) void gemm_nt_bias(
    const short* __restrict__ A, const short* __restrict__ B,
    const float* __restrict__ bias, float* __restrict__ out, int N) {
  const int tid = threadIdx.x;
  const int lane = tid & 63, wv = tid >> 6;
  const int m0 = blockIdx.x * 64 + (wv & 1) * 32;
  const int n0 = blockIdx.y * 64 + (wv >> 1) * 32;
  const int lm = lane & 15, q = lane >> 4;

  const short* a0p = A + (m0 + lm) * K + q * 8;
  const short* a1p = a0p + 16 * K;
  const short* b0p = B + (n0 + lm) * K + q * 8;
  const short* b1p = b0p + 16 * K;

  f32x4 c00 = {0.f,0.f,0.f,0.f}, c01 = {0.f,0.f,0.f,0.f};
  f32x4 c10 = {0.f,0.f,0.f,0.f}, c11 = {0.f,0.f,0.f,0.f};

#pragma unroll
  for (int kk = 0; kk < K; kk += 32) {
    s16x8 a0 = *(const s16x8*)(a0p + kk);
    s16x8 a1 = *(const s16x8*)(a1p + kk);
    s16x8 b0 = *(const s16x8*)(b0p + kk);
    s16x8 b1 = *(const s16x8*)(b1p + kk);
    c00 = mfma16(a0, b0, c00);
    c01 = mfma16(a0, b1, c01);
    c10 = mfma16(a1, b0, c10);
    c11 = mfma16(a1, b1, c11);
  }

  const int col0 = n0 + lm;
  const float bi0 = bias[col0], bi1 = bias[col0 + 16];
#pragma unroll
  for (int r = 0; r < 4; ++r) {
    int row = m0 + q * 4 + r;
    out[row * N + col0]        = c00[r] + bi0;
    out[row * N + col0 + 16]   = c01[r] + bi1;
    out[(row + 16) * N + col0]      = c10[r] + bi0;
    out[(row + 16) * N + col0 + 16] = c11[r] + bi1;
  }
}

// ---------------- recurrent kernel ----------------
// 256 WGs of 64 threads (1 wave). group g = bid&7 owns batch rows [8g,8g+8);
// col-wg c = bid>>3 owns hidden cols [32c,32c+32). wR slice lives in 256 regs.
//
// Protocol (R4, kept): tag-in-data, SYSTEM scope throughout. staging32 words
// = (bf16 << 16) | tag. Producer at step t writes slot t&1 with tag t+1 via
// relaxed system stores and proceeds — no ack, no flag. Consumer at step t
// reads slot (t+1)&1 expecting tag t; each aligned dword is single-copy
// atomic, so tag==t proves the value is step-t's. Overwrite safety: seeing
// tag t from peer P proves P issued its step t-1 stores, which follow P's
// reads of slot t&1 in program order. Own chunk comes from LDS (masked).
//
// R5 fix: READINESS PROBE before any data load. R4 issued its prefetch ring
// at step entry — always stale (peers hadn't stored yet) — so all 8 batches
// paid >=1 serial retry round-trip interleaved with the MFMA loop (~3 us of
// the 7.1 us step). Now: spin on a 1-u64-per-lane wave-wide sample (64
// samples cover all 32 chunks x2) until all tags == t; only then issue the
// ring. Full per-dword validation stays as the correctness backstop against
// relaxed store reordering (rarely fires now).

__global__ __launch_bounds__(64, 1) void rnn_recur(
    const float* __restrict__ wR,     // [1024][1024] fp32, k-major
    float* __restrict__ hid,          // [512*64][1024] fp32: xp on entry, h on exit
    short* __restrict__ hs_bf,        // [512*64][1024] bf16 copy of h (for phase C)
    unsigned* __restrict__ staging)   // [2][64][1024] tagged dwords
{
  __shared__ short lh[256];           // 8 rows x 32 cols bf16 repack buffer

  const int lane = threadIdx.x;
  const int g = blockIdx.x & 7;
  const int c = blockIdx.x >> 3;
  const int m = lane & 15, q = lane >> 4;
  const int rowbase = g * 8;
  const int colbase = c * 32;

  // --- one-time: pack wR[:, colbase..colbase+32) into B-fragments in registers ---
  s16x8 bf[32][2];
#pragma unroll
  for (int cc = 0; cc < 32; ++cc) {
#pragma unroll
    for (int tn = 0; tn < 2; ++tn) {
      const int kb = cc * 32 + q * 8;
      const int n = colbase + tn * 16 + m;
      s16x8 v;
#pragma unroll
      for (int j = 0; j < 8; ++j) v[j] = f2bf(wR[(kb + j) * 1024 + n]);
      bf[cc][tn] = v;
    }
  }

  const int arow = rowbase + (m & 7);  // lanes m>=8 duplicate rows 0..7
  const int gr = rowbase + q * 4;      // epilogue rows (valid when q<2)
  const int lr = q * 4;                // local row base in lh
  // packed-store mapping: lane i handles 4 dwords = 4 cols: row i>>3, col (i&7)*4
  const int prow = lane >> 3, pcol = (lane & 7) * 4;

  const u64 TAGMASK = 0x0000FFFF0000FFFFull;
  const int pchunk = lane & 31;            // probe chunk for this lane
  const bool pown = (pchunk == c);         // own chunk: masked from probe when t>0

#pragma unroll 1
  for (int t = 0; t < 512; ++t) {
    const int tb = t * 64;

    // prefetch xp (independent of the protocol) to hide HBM latency
    float xp0[4] = {0.f,0.f,0.f,0.f}, xp1[4] = {0.f,0.f,0.f,0.f};
    if (q < 2) {
#pragma unroll
      for (int r = 0; r < 4; ++r) {
        int ro = (tb + gr + r) * 1024;
        xp0[r] = hid[ro + colbase + m];
        xp1[r] = hid[ro + colbase + 16 + m];
      }
    }

    const unsigned* stg = staging + (((t + 1) & 1) << 16) + arow * 1024 + q * 8;
    const u64 expect = ((u64)(unsigned)t << 32) | (unsigned)t;
    // own chunk from LDS (lh holds h(t-1) at this point; t=0 uses init data)
    s16x8 ownfrag = *(const s16x8*)&lh[(m & 7) * 32 + q * 8];

    // ---- R5 readiness probe: don't touch data until tags show step t ----
    {
      const u64* paddr = (const u64*)(stg + pchunk * 32);
      const bool skip = pown && (t > 0);
      for (;;) {
        u64 v = __hip_atomic_load(paddr, __ATOMIC_RELAXED, __HIP_MEMORY_SCOPE_SYSTEM);
        if (__all(skip || ((v & TAGMASK) == expect))) break;
        __builtin_amdgcn_s_sleep(2);
      }
      asm volatile("" ::: "memory");  // no data-load hoisting above the probe
    }

    f32x4 cA0 = {0.f,0.f,0.f,0.f}, cA1 = {0.f,0.f,0.f,0.f};
    f32x4 cB0 = {0.f,0.f,0.f,0.f}, cB1 = {0.f,0.f,0.f,0.f};

    // 8 batches of 4 chunks, 3-deep prefetch ring. Batch b dwords:
    // chunk cc = 4b+k4 at stg + cc*32, lane's 8 dwords as 4x 8B atomic loads.
    u64 raw[3][16];
#pragma unroll
    for (int i = 0; i < 16; ++i)
      raw[0][i] = __hip_atomic_load((const u64*)(stg + (i >> 2) * 32 + (i & 3) * 2),
                                    __ATOMIC_RELAXED, __HIP_MEMORY_SCOPE_SYSTEM);
#pragma unroll
    for (int i = 0; i < 16; ++i)
      raw[1][i] = __hip_atomic_load((const u64*)(stg + 128 + (i >> 2) * 32 + (i & 3) * 2),
                                    __ATOMIC_RELAXED, __HIP_MEMORY_SCOPE_SYSTEM);

#pragma unroll
    for (int b = 0; b < 8; ++b) {
      const int rb = b % 3;
      if (b + 2 < 8) {
        const int rn = (b + 2) % 3;
#pragma unroll
        for (int i = 0; i < 16; ++i)
          raw[rn][i] = __hip_atomic_load(
              (const u64*)(stg + (b + 2) * 128 + (i >> 2) * 32 + (i & 3) * 2),
              __ATOMIC_RELAXED, __HIP_MEMORY_SCOPE_SYSTEM);
      }
      // validate batch b's tags (own chunk masked when t>0); retry-reload on miss
      // (backstop vs relaxed store reordering; rare after the probe)
      for (;;) {
        u64 err = 0;
#pragma unroll
        for (int k4 = 0; k4 < 4; ++k4) {
          const int cc = b * 4 + k4;
          u64 e = 0;
#pragma unroll
          for (int j = 0; j < 4; ++j)
            e |= (raw[rb][k4 * 4 + j] & TAGMASK) ^ expect;
          if (!(cc == c && t > 0)) err |= e;
        }
        if (!__any(err != 0ull)) break;
        __builtin_amdgcn_s_sleep(1);
#pragma unroll
        for (int i = 0; i < 16; ++i)
          raw[rb][i] = __hip_atomic_load(
              (const u64*)(stg + b * 128 + (i >> 2) * 32 + (i & 3) * 2),
              __ATOMIC_RELAXED, __HIP_MEMORY_SCOPE_SYSTEM);
      }
      // compact high-16 value bits -> bf16 fragments, MFMA
#pragma unroll
      for (int k4 = 0; k4 < 4; ++k4) {
        const int cc = b * 4 + k4;
        union { unsigned d[4]; s16x8 s; } fr;
#pragma unroll
        for (int j = 0; j < 4; ++j) {
          u64 v = raw[rb][k4 * 4 + j];
          fr.d[j] = (unsigned)((v >> 16) & 0xFFFFull) | ((unsigned)(v >> 48) << 16);
        }
        s16x8 a = (cc == c && t > 0) ? ownfrag : fr.s;
        if (cc & 1) {
          cB0 = mfma16(a, bf[cc][0], cB0);
          cB1 = mfma16(a, bf[cc][1], cB1);
        } else {
          cA0 = mfma16(a, bf[cc][0], cA0);
          cA1 = mfma16(a, bf[cc][1], cA1);
        }
      }
    }
    f32x4 s0 = cA0 + cB0;
    f32x4 s1 = cA1 + cB1;

    // tanh + repack through LDS (512B, single wave)
    float h0v[4], h1v[4];
    if (q < 2) {
#pragma unroll
      for (int r = 0; r < 4; ++r) {
        h0v[r] = fast_tanh(s0[r] + xp0[r]);
        h1v[r] = fast_tanh(s1[r] + xp1[r]);
        lh[(lr + r) * 32 + m]      = f2bf(h0v[r]);
        lh[(lr + r) * 32 + 16 + m] = f2bf(h1v[r]);
      }
    }
    __syncthreads();

    // pack 4 cols with tag t+1 -> staging (the store IS the handoff; no ack,
    // no flag) + raw bf16 -> hs_bf (phase C)
    long long pk = ((const long long*)lh)[lane];
    {
      const unsigned tp1 = (unsigned)(t + 1);
      const u64 pkv = (u64)pk;
      unsigned w0 = ((unsigned)(pkv & 0xFFFFull) << 16) | tp1;
      unsigned w1 = ((unsigned)((pkv >> 16) & 0xFFFFull) << 16) | tp1;
      unsigned w2 = ((unsigned)((pkv >> 32) & 0xFFFFull) << 16) | tp1;
      unsigned w3 = ((unsigned)((pkv >> 48) & 0xFFFFull) << 16) | tp1;
      u64 q0 = (u64)w0 | ((u64)w1 << 32);
      u64 q1 = (u64)w2 | ((u64)w3 << 32);
      unsigned* sp = staging + ((t & 1) << 16) + (rowbase + prow) * 1024 + colbase + pcol;
      __hip_atomic_store((u64*)sp,       q0, __ATOMIC_RELAXED, __HIP_MEMORY_SCOPE_SYSTEM);
      __hip_atomic_store((u64*)(sp + 2), q1, __ATOMIC_RELAXED, __HIP_MEMORY_SCOPE_SYSTEM);
      *(long long*)(hs_bf + (tb + rowbase + prow) * 1024 + colbase + pcol) = pk;
    }
    __syncthreads();  // lh reads done before next step's writes

    // non-protocol fp32 h stores drain whenever (kernel-end flush covers phase C)
    if (q < 2) {
#pragma unroll
      for (int r = 0; r < 4; ++r) {
        int ro = (tb + gr + r) * 1024;
        hid[ro + colbase + m] = h0v[r];
        hid[ro + colbase + 16 + m] = h1v[r];
      }
    }
  }
}

// ---------------- host ----------------

extern "C" void kernel_launch(void* const* d_in, const int* in_sizes, int n_in,
                              void* d_out, int out_size, void* d_ws, size_t ws_size,
                              hipStream_t stream) {
  const float* x  = (const float*)d_in[0];
  const float* h0 = (const float*)d_in[1];
  const float* wI = (const float*)d_in[2];
  const float* wR = (const float*)d_in[3];
  const float* wO = (const float*)d_in[4];
  const float* bR = (const float*)d_in[5];
  const float* bO = (const float*)d_in[6];

  float* outputs = (float*)d_out;                    // [512*64][256]
  float* hid = outputs + 512 * 64 * 256;             // [512*64][1024]

  // workspace layout (~85 MB, unchanged footprint):
  short* x_bf    = (short*)d_ws;                     // 8,388,608 bf16
  short* wI_bf   = x_bf + 8388608;                   // 262,144
  short* wO_bf   = wI_bf + 262144;                   // 262,144
  short* hs_bf   = wO_bf + 262144;                   // 33,554,432
  // staging32 overlays x_bf (512 KB): x_bf is dead after phase A, and
  // init_staging32 runs after phase A. Next graph iteration rewrites x_bf
  // first (cvt), then re-inits staging32 after phase A — order is safe.
  unsigned* staging32 = (unsigned*)d_ws;             // [2][64][1024] dwords

  cvt_bf16x4<<<8192, 256, 0, stream>>>(x, x_bf, 2097152);
  cvt_bf16x4<<<256, 256, 0, stream>>>(wI, wI_bf, 65536);
  cvt_bf16x4<<<256, 256, 0, stream>>>(wO, wO_bf, 65536);

  // Phase A: xp = x*wI^T + bR  -> hidden region (in-place seed for recurrence)
  gemm_nt_bias<256><<<dim3(512, 16), 256, 0, stream>>>(x_bf, wI_bf, bR, hid, 1024);
  // staging init AFTER phase A (x_bf consumed; region reused)
  init_staging32<<<512, 256, 0, stream>>>(h0, staging32);
  // Phase B: sequential recurrence
  rnn_recur<<<256, 64, 0, stream>>>(wR, hid, hs_bf, staging32);
  // Phase C: outputs = h*wO^T + bO
  gemm_nt_bias<1024><<<dim3(512, 4), 256, 0, stream>>>(hs_bf, wO_bf, bO, outputs, 256);
}

// Round 6
// 2226.926 us; speedup vs baseline: 1.8655x; 1.8655x over previous
//
#include <hip/hip_runtime.h>
#include <math.h>

// Problem constants: T=512, B=64, I=256, H=1024, O=256
// d_out layout: outputs [512*64][256] fp32, then hidden_states [512*64][1024] fp32.

typedef __attribute__((ext_vector_type(8))) short s16x8;
typedef __attribute__((ext_vector_type(4))) short s16x4;
typedef __attribute__((ext_vector_type(4))) float f32x4;
typedef unsigned long long u64;

__device__ __forceinline__ short f2bf(float f) {
  union { float f; unsigned u; } v; v.f = f;
  unsigned r = v.u + 0x7FFFu + ((v.u >> 16) & 1u);  // RNE
  return (short)(r >> 16);
}

__device__ __forceinline__ f32x4 mfma16(s16x8 a, s16x8 b, f32x4 c) {
  return __builtin_amdgcn_mfma_f32_16x16x32_bf16(a, b, c, 0, 0, 0);
}

// tanh via v_exp_f32: t = 1 - 2/(e^{2x}+1). Monotone-safe at +-inf, no NaN.
__device__ __forceinline__ float fast_tanh(float x) {
  float e = __expf(2.0f * x);
  return 1.0f - 2.0f * __builtin_amdgcn_rcpf(e + 1.0f);
}

// ---------------- converters / init ----------------

__global__ void cvt_bf16x4(const float* __restrict__ in, short* __restrict__ out, int n4) {
  int i = blockIdx.x * 256 + threadIdx.x;
  if (i < n4) {
    const float4 v = ((const float4*)in)[i];
    s16x4 o = { f2bf(v.x), f2bf(v.y), f2bf(v.z), f2bf(v.w) };
    ((s16x4*)out)[i] = o;
  }
}

// staging: [2 slots][64 rows][1024] bf16. Slot 1 = h_{-1} = broadcast h0.
__global__ void init_staging(const float* __restrict__ h0, short* __restrict__ staging) {
  int i = blockIdx.x * 256 + threadIdx.x;  // 2*64*1024 = 131072
  if (i < 131072) {
    int slot = i >> 16;
    int k = i & 1023;
    staging[i] = (slot == 1) ? f2bf(h0[k]) : (short)0;
  }
}

// ---------------- generic NT GEMM: out[M][N] = A[M][K](bf16) * B[N][K](bf16)^T + bias ----------------

template <int K>
__global__ __launch_bounds__(256) void gemm_nt_bias(
    const short* __restrict__ A, const short* __restrict__ B,
    const float* __restrict__ bias, float* __restrict__ out, int N) {
  const int tid = threadIdx.x;
  const int lane = tid & 63, wv = tid >> 6;
  const int m0 = blockIdx.x * 64 + (wv & 1) * 32;
  const int n0 = blockIdx.y * 64 + (wv >> 1) * 32;
  const int lm = lane & 15, q = lane >> 4;

  const short* a0p = A + (m0 + lm) * K + q * 8;
  const short* a1p = a0p + 16 * K;
  const short* b0p = B + (n0 + lm) * K + q * 8;
  const short* b1p = b0p + 16 * K;

  f32x4 c00 = {0.f,0.f,0.f,0.f}, c01 = {0.f,0.f,0.f,0.f};
  f32x4 c10 = {0.f,0.f,0.f,0.f}, c11 = {0.f,0.f,0.f,0.f};

#pragma unroll
  for (int kk = 0; kk < K; kk += 32) {
    s16x8 a0 = *(const s16x8*)(a0p + kk);
    s16x8 a1 = *(const s16x8*)(a1p + kk);
    s16x8 b0 = *(const s16x8*)(b0p + kk);
    s16x8 b1 = *(const s16x8*)(b1p + kk);
    c00 = mfma16(a0, b0, c00);
    c01 = mfma16(a0, b1, c01);
    c10 = mfma16(a1, b0, c10);
    c11 = mfma16(a1, b1, c11);
  }

  const int col0 = n0 + lm;
  const float bi0 = bias[col0], bi1 = bias[col0 + 16];
#pragma unroll
  for (int r = 0; r < 4; ++r) {
    int row = m0 + q * 4 + r;
    out[row * N + col0]        = c00[r] + bi0;
    out[row * N + col0 + 16]   = c01[r] + bi1;
    out[(row + 16) * N + col0]      = c10[r] + bi0;
    out[(row + 16) * N + col0 + 16] = c11[r] + bi1;
  }
}

// ---------------- recurrent kernel ----------------
// R6 restructure: 64 WGs of 256 threads (4 waves). group g = bid&7 owns batch
// rows [8g,8g+8); WG w = bid>>3 owns hidden cols [128w,128w+128); wave v owns
// cols [128w+32v, +32) with the SAME per-wave wR register layout (bf[32][2])
// and MFMA fragments as the verified 1-wave kernel.
//
// Why: R1-R5 counters show step time ~7.3us with MFMA+VALU only ~0.7us. The
// stall is the protocol load burst: every wave issued 128 scattered system-
// scope (L1/L2-bypass) loads -> ~1024 fine-grain fabric transactions per wave
// per step, uncoalescible by caches. R6 loads the 16KB h-tile ONCE per WG,
// cooperatively + contiguously (64B/thread), into a swizzled LDS tile shared
// by 4 waves -> 16x fewer fabric transactions per group per step.
//
// Ordering protocol = the R1/R3-VERIFIED pattern (no tags, no speculation):
// producer: staging stores (system, relaxed) -> s_waitcnt vmcnt(0) per wave ->
// __syncthreads -> tid0 stores flags[g][w]=t+1 (relaxed system store).
// consumer: polls the 8 flag words (wave-wide, lane&7) until all >= t, then
// loads. flag>=t proves peers' step t-1 staging stores are acked at the
// coherence point AND their step t-1 reads (program-order earlier) are done,
// so slot t&1 is safe to read and (later) overwrite. Slot parity ring of 2.

__global__ __launch_bounds__(256, 1) void rnn_recur(
    const float* __restrict__ wR,     // [1024][1024] fp32, k-major
    float* __restrict__ hid,          // [512*64][1024] fp32: xp on entry, h on exit
    short* __restrict__ hs_bf,        // [512*64][1024] bf16 copy of h (for phase C)
    short* __restrict__ staging,      // [2][64][1024] bf16 ring of h
    int* __restrict__ flags)          // [8][8] per-WG step words
{
  __shared__ short tile[8 * 1024];    // 16 KB swizzled h tile (8 rows x 1024 cols)
  __shared__ short lh[4 * 256];       // per-wave 8x32 repack buffers (4 x 512 B)

  const int tid = threadIdx.x;
  const int lane = tid & 63;
  const int v = tid >> 6;             // wave 0..3
  const int g = blockIdx.x & 7;
  const int w = blockIdx.x >> 3;      // 0..7
  const int m = lane & 15, q = lane >> 4;
  const int rowbase = g * 8;
  const int colbase = w * 128 + v * 32;

  // --- one-time: pack wR[:, colbase..colbase+32) into B-fragments in registers ---
  s16x8 bf[32][2];
#pragma unroll
  for (int cc = 0; cc < 32; ++cc) {
#pragma unroll
    for (int tn = 0; tn < 2; ++tn) {
      const int kb = cc * 32 + q * 8;
      const int n = colbase + tn * 16 + m;
      s16x8 vv;
#pragma unroll
      for (int j = 0; j < 8; ++j) vv[j] = f2bf(wR[(kb + j) * 1024 + n]);
      bf[cc][tn] = vv;
    }
  }

  const int gr = rowbase + q * 4;     // epilogue rows (valid when q<2)
  const int lr = q * 4;               // local row base in lh
  // packed-store mapping: lane i covers 8 B = 4 cols: row i>>3, col (i&7)*4
  const int prow = lane >> 3, pcol = (lane & 7) * 4;
  short* lhv = lh + v * 256;

  // cooperative tile load indexing: thread i loads 64 contiguous bytes of the
  // [8][1024] bf16 tile: row = tid>>5, col-span = (tid&31)*32 shorts.
  const int srow = tid >> 5;
  const int scol = (tid & 31) * 32;
  // LDS swizzle: 64B-granular XOR of row into byte addr bit 6-8. ds_read_b128
  // (16B units): unit = row*128 + ((cc*4+q) ^ row*4) -> 32 distinct mod 32
  // across the 32 unique (row,q) pairs -> conflict-free; 2x dup = broadcast.
  const int arow = m & 7;
  const char* trd = (const char*)tile + arow * 2048;
  const int axor = arow << 6;

  const int* fpoll = flags + g * 8 + (lane & 7);
  int* fmine = flags + g * 8 + w;

#pragma unroll 1
  for (int t = 0; t < 512; ++t) {
    const int tb = t * 64;

    // prefetch xp (independent of the protocol) to hide HBM latency
    float xp0[4] = {0.f,0.f,0.f,0.f}, xp1[4] = {0.f,0.f,0.f,0.f};
    if (q < 2) {
#pragma unroll
      for (int r = 0; r < 4; ++r) {
        int ro = (tb + gr + r) * 1024;
        xp0[r] = hid[ro + colbase + m];
        xp1[r] = hid[ro + colbase + 16 + m];
      }
    }

    if (t > 0) {
      // all 8 producer WGs of this group must have finished step t-1
      for (;;) {
        int fv = __hip_atomic_load(fpoll, __ATOMIC_RELAXED, __HIP_MEMORY_SCOPE_SYSTEM);
        if (__all(fv >= t)) break;
        __builtin_amdgcn_s_sleep(1);
      }
      asm volatile("" ::: "memory");  // no load hoisting above the poll
    }

    // ---- cooperative 16 KB tile load: contiguous global -> swizzled LDS ----
    {
      const short* src = staging + (((t + 1) & 1) << 16) + (rowbase + srow) * 1024 + scol;
      u64 tmp[8];
#pragma unroll
      for (int j = 0; j < 8; ++j)
        tmp[j] = __hip_atomic_load((const u64*)(src + j * 4),
                                   __ATOMIC_RELAXED, __HIP_MEMORY_SCOPE_SYSTEM);
      char* dst = (char*)tile + srow * 2048 + ((scol * 2) ^ (srow << 6));
#pragma unroll
      for (int j = 0; j < 8; ++j)
        *(u64*)(dst + j * 8) = tmp[j];
    }
    __syncthreads();  // B1: tile ready for all 4 waves

    // ---- MFMA over 32 k-chunks from LDS ----
    f32x4 cA0 = {0.f,0.f,0.f,0.f}, cA1 = {0.f,0.f,0.f,0.f};
    f32x4 cB0 = {0.f,0.f,0.f,0.f}, cB1 = {0.f,0.f,0.f,0.f};
#pragma unroll
    for (int cc = 0; cc < 32; ++cc) {
      s16x8 a = *(const s16x8*)(trd + ((cc * 64 + q * 16) ^ axor));
      if (cc & 1) {
        cB0 = mfma16(a, bf[cc][0], cB0);
        cB1 = mfma16(a, bf[cc][1], cB1);
      } else {
        cA0 = mfma16(a, bf[cc][0], cA0);
        cA1 = mfma16(a, bf[cc][1], cA1);
      }
    }
    f32x4 s0 = cA0 + cB0;
    f32x4 s1 = cA1 + cB1;

    // tanh + repack through per-wave LDS buffer
    float h0v[4], h1v[4];
    if (q < 2) {
#pragma unroll
      for (int r = 0; r < 4; ++r) {
        h0v[r] = fast_tanh(s0[r] + xp0[r]);
        h1v[r] = fast_tanh(s1[r] + xp1[r]);
        lhv[(lr + r) * 32 + m]      = f2bf(h0v[r]);
        lhv[(lr + r) * 32 + 16 + m] = f2bf(h1v[r]);
      }
    }
    __syncthreads();  // B_pack: lhv writes visible (also keeps waves loosely in step)

    // one 8B packed value per lane -> staging (protocol) + hs_bf (phase C)
    long long pk = ((const long long*)lhv)[lane];
    {
      short* sp = staging + ((t & 1) << 16) + (rowbase + prow) * 1024 + colbase + pcol;
      __hip_atomic_store((u64*)sp, (u64)pk, __ATOMIC_RELAXED, __HIP_MEMORY_SCOPE_SYSTEM);
      *(long long*)(hs_bf + (tb + rowbase + prow) * 1024 + colbase + pcol) = pk;
    }

    asm volatile("s_waitcnt vmcnt(0)" ::: "memory");  // staging stores acked at L3
    __syncthreads();  // B2: all 4 waves acked
    if (tid == 0)
      __hip_atomic_store(fmine, t + 1, __ATOMIC_RELAXED, __HIP_MEMORY_SCOPE_SYSTEM);

    // non-protocol fp32 h stores drain whenever (kernel-end flush covers phase C)
    if (q < 2) {
#pragma unroll
      for (int r = 0; r < 4; ++r) {
        int ro = (tb + gr + r) * 1024;
        hid[ro + colbase + m] = h0v[r];
        hid[ro + colbase + 16 + m] = h1v[r];
      }
    }
  }
}

// ---------------- host ----------------

extern "C" void kernel_launch(void* const* d_in, const int* in_sizes, int n_in,
                              void* d_out, int out_size, void* d_ws, size_t ws_size,
                              hipStream_t stream) {
  const float* x  = (const float*)d_in[0];
  const float* h0 = (const float*)d_in[1];
  const float* wI = (const float*)d_in[2];
  const float* wR = (const float*)d_in[3];
  const float* wO = (const float*)d_in[4];
  const float* bR = (const float*)d_in[5];
  const float* bO = (const float*)d_in[6];

  float* outputs = (float*)d_out;                    // [512*64][256]
  float* hid = outputs + 512 * 64 * 256;             // [512*64][1024]

  // workspace layout: ~85.7 MB total
  short* x_bf    = (short*)d_ws;                     // 8,388,608 bf16
  short* wI_bf   = x_bf + 8388608;                   // 262,144
  short* wO_bf   = wI_bf + 262144;                   // 262,144
  short* hs_bf   = wO_bf + 262144;                   // 33,554,432
  short* staging = hs_bf + 33554432;                 // 131,072 bf16
  int*   flags   = (int*)(staging + 131072);         // [8][8] step words

  hipMemsetAsync(flags, 0, 64 * sizeof(int), stream);
  cvt_bf16x4<<<8192, 256, 0, stream>>>(x, x_bf, 2097152);
  cvt_bf16x4<<<256, 256, 0, stream>>>(wI, wI_bf, 65536);
  cvt_bf16x4<<<256, 256, 0, stream>>>(wO, wO_bf, 65536);
  init_staging<<<512, 256, 0, stream>>>(h0, staging);

  // Phase A: xp = x*wI^T + bR  -> hidden region (in-place seed for recurrence)
  gemm_nt_bias<256><<<dim3(512, 16), 256, 0, stream>>>(x_bf, wI_bf, bR, hid, 1024);
  // Phase B: sequential recurrence (64 WGs x 256 threads)
  rnn_recur<<<64, 256, 0, stream>>>(wR, hid, hs_bf, staging, flags);
  // Phase C: outputs = h*wO^T + bO
  gemm_nt_bias<1024><<<dim3(512, 4), 256, 0, stream>>>(hs_bf, wO_bf, bO, outputs, 256);
}